// Round 2
// baseline (5809.681 us; speedup 1.0000x reference)
//
#include <hip/hip_runtime.h>
#include <stdint.h>

// AutoregressiveRAM: 4095 serial steps of an 8192-neuron weightless NN.
// Persistent 16-block kernel; per-step state (8192 bits = 256 words) exchanged
// via tagged (data32 lo, tag32 hi) 64-bit agent-scope atomics in d_ws.
// Transition RAM prepacked to bits (32MB f32 -> 1MB) so lookups stay cached.
//
// Protocol proof sketch: step i polls slot[(i-1)&1] for tag i, publishes its
// own words to slot[i&1] with tag i+1 AFTER its poll succeeded. Poll success
// at step i requires every block's tag-i publish, which happens after that
// block finished READING slot[i&1] at step i-1 -> no overwrite race. Exact
// tag equality means stale/garbage mailbox contents can never satisfy a
// wait; a memset node additionally zeroes the mailbox every replay.

#define BITS   8192
#define NBT    10
#define NBLK   16
#define TPB    512
#define NPB    (BITS / NBLK)   // 512 neurons per block (1 per thread)
#define SWORDS 256             // 8192 state bits / 32
#define WPB    (NPB / 32)      // 16 state words owned per block
#define FUSE   (1 << 12)       // bounded spin: protocol slack is ~10 iters

__global__ void pack_kernel(const float* __restrict__ tm, uint32_t* __restrict__ packed) {
    // 8192*1024 floats -> 262144 packed u32 words. One float per thread.
    int tid = blockIdx.x * blockDim.x + threadIdx.x;
    float v = tm[tid];
    unsigned long long m = __ballot(v > 0.5f);
    int lane = tid & 63;
    if ((lane & 31) == 0) {
        packed[tid >> 5] = (lane == 0) ? (uint32_t)m : (uint32_t)(m >> 32);
    }
}

__global__ __launch_bounds__(TPB) void ram_step_kernel(
    const int* __restrict__ conn,        // [8192][10]
    const float* __restrict__ init_mem,  // [8192][16]
    const uint32_t* __restrict__ packedT,// [8192][32]
    unsigned long long* __restrict__ pairs, // [2][SWORDS] (data lo32, tag hi32)
    float* __restrict__ out,             // [length][8192]
    int length)
{
    const int b = blockIdx.x;
    const int t = threadIdx.x;
    const int lane = t & 63;
    const int n = b * NPB + t;           // this thread's neuron

    __shared__ uint32_t st[SWORDS + 1];  // full state + pos-bits word

    // Connections are static: keep in registers for the whole run.
    int c[NBT];
#pragma unroll
    for (int j = 0; j < NBT; ++j) c[j] = conn[n * NBT + j];

    // ---- step 0: pos bits of 0 are all zero -> addr 0 -> initial_memory[:,0]
    float v0 = init_mem[n << 4];
    out[n] = v0;
    int bit = (v0 > 0.5f) ? 1 : 0;
    unsigned long long m = __ballot(bit);
    const int gw = b * WPB + (t >> 6) * 2;  // this wave's global state-word base
    if (lane == 0) {
        const unsigned long long tag = 1ull << 32;  // tag(step s) = s+1
        __hip_atomic_store(&pairs[gw],     tag | (uint32_t)m,
                           __ATOMIC_RELAXED, __HIP_MEMORY_SCOPE_AGENT);
        __hip_atomic_store(&pairs[gw + 1], tag | (uint32_t)(m >> 32),
                           __ATOMIC_RELAXED, __HIP_MEMORY_SCOPE_AGENT);
        st[gw]     = (uint32_t)m;        // own slice goes straight to LDS
        st[gw + 1] = (uint32_t)(m >> 32);
    }

    for (int i = 1; i < length; ++i) {
        const int parity = (i - 1) & 1;
        const uint32_t want = (uint32_t)i;          // waiting for tag of step i-1

        if (t == 0) {
            // pos bits of step i: x[8192+j] = (i >> (3-j)) & 1
            st[SWORDS] = ((i >> 3) & 1) | (((i >> 2) & 1) << 1) |
                         (((i >> 1) & 1) << 2) | ((i & 1) << 3);
        }
        if (t < SWORDS && (t >> 4) != b) {          // poll everyone else's words
            unsigned long long* p = &pairs[parity * SWORDS + t];
            unsigned long long pv;
            int fuse = 0;
            do {
                pv = __hip_atomic_load(p, __ATOMIC_RELAXED, __HIP_MEMORY_SCOPE_AGENT);
            } while ((uint32_t)(pv >> 32) != want && ++fuse < FUSE);
            st[t] = (uint32_t)pv;
        }
        __syncthreads();

        // gather 10 bits -> 10-bit address (conn[0] is MSB)
        uint32_t addr = 0;
#pragma unroll
        for (int j = 0; j < NBT; ++j) {
            int cc = c[j];
            uint32_t w = st[cc >> 5];
            addr = (addr << 1) | ((w >> (cc & 31)) & 1u);
        }
        uint32_t pw = packedT[(n << 5) + (addr >> 5)];
        bit = (pw >> (addr & 31)) & 1;
        out[(size_t)i * BITS + n] = (float)bit;

        // publish own slice for step i ASAP (poll at step i already proved all
        // blocks finished reading this slot at step i-1 -> safe to overwrite)
        m = __ballot(bit);
        if (lane == 0) {
            const unsigned long long tag = ((unsigned long long)(i + 1)) << 32;
            const int base = (i & 1) * SWORDS + gw;
            __hip_atomic_store(&pairs[base],     tag | (uint32_t)m,
                               __ATOMIC_RELAXED, __HIP_MEMORY_SCOPE_AGENT);
            __hip_atomic_store(&pairs[base + 1], tag | (uint32_t)(m >> 32),
                               __ATOMIC_RELAXED, __HIP_MEMORY_SCOPE_AGENT);
        }
        __syncthreads();                 // everyone done reading step i-1 state
        if (lane == 0) {                 // now safe to refresh own LDS words
            st[gw]     = (uint32_t)m;
            st[gw + 1] = (uint32_t)(m >> 32);
        }
    }
}

extern "C" void kernel_launch(void* const* d_in, const int* in_sizes, int n_in,
                              void* d_out, int out_size, void* d_ws, size_t ws_size,
                              hipStream_t stream) {
    const float* tm = (const float*)d_in[0];     // transition_memory [8192][1024]
    const float* im = (const float*)d_in[1];     // initial_memory    [8192][16]
    const int*   tc = (const int*)d_in[2];       // transition_connections [8192][10]
    // d_in[3] (initial_connections) is provably unused: pos_bits(0)==0 -> addr 0.
    const int length = out_size / BITS;

    uint32_t* packed = (uint32_t*)d_ws;                                   // 1 MB
    unsigned long long* pairs =
        (unsigned long long*)((char*)d_ws + (1 << 20));                   // 4 KB

    // Clean mailbox every call/replay (graph-capturable memset node).
    hipMemsetAsync(pairs, 0, 2 * SWORDS * sizeof(unsigned long long), stream);

    // Pack transition RAM to bits: 8192*1024 floats, 1 thread each.
    pack_kernel<<<dim3((BITS * 1024) / 256), dim3(256), 0, stream>>>(tm, packed);

    // Persistent recurrence kernel: 16 blocks (always co-resident on 256 CUs).
    ram_step_kernel<<<dim3(NBLK), dim3(TPB), 0, stream>>>(
        tc, im, packed, pairs, (float*)d_out, length);
}